// Round 3
// baseline (197.617 us; speedup 1.0000x reference)
//
#include <hip/hip_runtime.h>
#include <math.h>

typedef __attribute__((ext_vector_type(8)))  short          short8;
typedef __attribute__((ext_vector_type(8)))  unsigned short ushort8;
typedef __attribute__((ext_vector_type(8)))  _Float16       half8;
typedef __attribute__((ext_vector_type(16))) float          f32x16;

#define Bb 16
#define Cc 256
#define Tt 2048

#define LOG2E 1.4426950408889634f

// ---- workspace layout (bytes) ----
#define WH_OFF    0u                         // ushort [320][256] bf16-hi of W
#define WL_OFF    163840u                    // ushort [320][256] bf16-lo of W
#define BALL_OFF  327680u                    // fp32 [320]
#define QTF_OFF   328960u                    // ushort [16][2048][32] fp16 bits, [t][c]  (Q pre-scaled by log2e)
#define KTF_OFF   (QTF_OFF + 2097152u)
#define VBF_OFF   (KTF_OFF + 2097152u)       // ushort [16][256][2048] bf16 bits, [c][t]

__device__ __forceinline__ unsigned short f2bf(float f) {
  union { float f; unsigned u; } v; v.f = f;
  unsigned r = v.u + 0x7fffu + ((v.u >> 16) & 1u);   // RNE
  return (unsigned short)(r >> 16);
}
__device__ __forceinline__ float bf2f(unsigned short h) {
  union { unsigned u; float f; } v; v.u = ((unsigned)h) << 16;
  return v.f;
}
__device__ __forceinline__ unsigned short f2h(float f) {
  union { _Float16 h; unsigned short u; } v; v.h = (_Float16)f;
  return v.u;
}

// ---------------------------------------------------------------------------
// pack: W -> bf16 hi/lo planes [320][256] (+ bias fp32[320]).
// ---------------------------------------------------------------------------
__global__ __launch_bounds__(256) void pack_kernel(
    const float* __restrict__ Wq, const float* __restrict__ bq,
    const float* __restrict__ Wk, const float* __restrict__ bk,
    const float* __restrict__ Wv, const float* __restrict__ bv,
    char* ws) {
  unsigned short* WH = (unsigned short*)(ws + WH_OFF);
  unsigned short* WL = (unsigned short*)(ws + WL_OFF);
  float* ball = (float*)(ws + BALL_OFF);
  int o = blockIdx.x, c = threadIdx.x;
  float v;
  if (o < 32)      v = Wq[o * 256 + c];
  else if (o < 64) v = Wk[(o - 32) * 256 + c];
  else             v = Wv[(o - 64) * 256 + c];
  unsigned short hb = f2bf(v);
  WH[o * 256 + c] = hb;
  WL[o * 256 + c] = f2bf(v - bf2f(hb));
  if (c == 0) ball[o] = (o < 32) ? bq[o] : (o < 64 ? bk[o - 32] : bv[o - 64]);
}

// ---------------------------------------------------------------------------
// proj (MFMA): round-0 structure; Q epilogue pre-scales by log2e so attn
// can use native exp2 (v_exp_f32) without the per-element mul.
// ---------------------------------------------------------------------------
__global__ __launch_bounds__(256, 2) void proj_kernel(
    const float* __restrict__ x, char* ws) {
  __shared__ __align__(16) float xs[128 * 64];
  __shared__ __align__(16) unsigned short xth[64 * 136];
  __shared__ __align__(16) unsigned short xtl[64 * 136];

  const unsigned short* WH = (const unsigned short*)(ws + WH_OFF);
  const unsigned short* WL = (const unsigned short*)(ws + WL_OFF);
  const float* ball = (const float*)(ws + BALL_OFF);
  unsigned short* Qtf = (unsigned short*)(ws + QTF_OFF);
  unsigned short* Ktf = (unsigned short*)(ws + KTF_OFF);
  unsigned short* Vbf = (unsigned short*)(ws + VBF_OFF);

  const int b   = blockIdx.y;
  const int t0  = blockIdx.x * 64;
  const int tid = threadIdx.x;
  const int w    = tid >> 6;
  const int lane = tid & 63;
  const int m    = lane & 31;
  const int hh   = lane >> 5;

  const float* xb = x + ((size_t)b * 256) * 2048 + t0;

  f32x16 qkacc;
  f32x16 vacc[4];
  #pragma unroll
  for (int r = 0; r < 16; ++r) qkacc[r] = 0.f;
  #pragma unroll
  for (int j = 0; j < 4; ++j)
    #pragma unroll
    for (int r = 0; r < 16; ++r) vacc[j][r] = 0.f;

  #pragma unroll
  for (int r = 0; r < 8; ++r) {
    int idx = r * 256 + tid;
    int c = idx >> 4, f = idx & 15;
    *(float4*)&xs[c * 64 + 4 * f] = *(const float4*)&xb[(size_t)c * 2048 + 4 * f];
  }
  __syncthreads();

  const int tt = w & 1;
  const int qo = 32 * (w >> 1);

  #pragma unroll
  for (int half = 0; half < 2; ++half) {
    {
      const int t = lane;
      const int cq = w * 32;
      #pragma unroll
      for (int g = 0; g < 4; ++g) {
        ushort8 h8, l8;
        #pragma unroll
        for (int j = 0; j < 8; ++j) {
          float v = xs[(cq + g * 8 + j) * 64 + t];
          unsigned short hb = f2bf(v);
          h8[j] = hb;
          l8[j] = f2bf(v - bf2f(hb));
        }
        *(ushort8*)&xth[t * 136 + cq + g * 8] = h8;
        *(ushort8*)&xtl[t * 136 + cq + g * 8] = l8;
      }
    }
    __syncthreads();

    float4 pre[8];
    if (half == 0) {
      #pragma unroll
      for (int r = 0; r < 8; ++r) {
        int idx = r * 256 + tid;
        int c = idx >> 4, f = idx & 15;
        pre[r] = *(const float4*)&xb[(size_t)(128 + c) * 2048 + 4 * f];
      }
    }

    #pragma unroll
    for (int kk = 0; kk < 8; ++kk) {
      const int kl = kk * 16 + 8 * hh;
      const int kg = half * 128 + kl;
      short8 bh = *(const short8*)&xth[(32 * tt + m) * 136 + kl];
      short8 bl = *(const short8*)&xtl[(32 * tt + m) * 136 + kl];
      short8 ah = *(const short8*)&WH[(size_t)(qo + m) * 256 + kg];
      short8 al = *(const short8*)&WL[(size_t)(qo + m) * 256 + kg];
      qkacc = __builtin_amdgcn_mfma_f32_32x32x16_bf16(ah, bh, qkacc, 0, 0, 0);
      qkacc = __builtin_amdgcn_mfma_f32_32x32x16_bf16(ah, bl, qkacc, 0, 0, 0);
      qkacc = __builtin_amdgcn_mfma_f32_32x32x16_bf16(al, bh, qkacc, 0, 0, 0);
      #pragma unroll
      for (int j = 0; j < 4; ++j) {
        short8 av = *(const short8*)&WH[(size_t)(64 + 32 * (2 * j + (w >> 1)) + m) * 256 + kg];
        vacc[j] = __builtin_amdgcn_mfma_f32_32x32x16_bf16(av, bh, vacc[j], 0, 0, 0);
      }
    }

    if (half == 0) {
      #pragma unroll
      for (int r = 0; r < 8; ++r) {
        int idx = r * 256 + tid;
        int c = idx >> 4, f = idx & 15;
        *(float4*)&xs[c * 64 + 4 * f] = pre[r];
      }
      __syncthreads();
    }
  }

  // Q/K epilogue: single fp16 plane; Q pre-scaled by log2e
  {
    unsigned short* pt = (w < 2) ? Qtf : Ktf;
    const float qs = (w < 2) ? LOG2E : 1.0f;
    const int tcol = t0 + 32 * tt + m;
    #pragma unroll
    for (int r = 0; r < 16; ++r) {
      int orow = (r & 3) + 8 * (r >> 2) + 4 * hh;
      float v = (qkacc[r] + ball[qo + orow]) * qs;
      pt[((size_t)b * 2048 + tcol) * 32 + orow] = f2h(v);
    }
  }
  // V epilogue: bf16 [c][t]
  #pragma unroll
  for (int j = 0; j < 4; ++j) {
    const int vob = 64 + 32 * (2 * j + (w >> 1));
    #pragma unroll
    for (int r = 0; r < 16; ++r) {
      int orow = (r & 3) + 8 * (r >> 2) + 4 * hh;
      int o = vob + orow;
      float v = vacc[j][r] + ball[o];
      Vbf[((size_t)b * 256 + (o - 64)) * 2048 + t0 + 32 * tt + m] = f2bf(v);
    }
  }
}

// ---------------------------------------------------------------------------
// attn v6 = proven round-0 structure, minus the V LDS staging.
// V fragments are read directly from global (L2-resident, 1 MB per batch);
// by the XOR-swizzle identity vk==uu these loads are byte-identical to what
// the old VS path delivered. Removes 16 LDS ops/iter + 64 KB LDS + vpre regs.
// Everything else (untransposed QK, scalar Ps writes, sacc[16], f2bf,
// __syncthreads, shfl-tree rowsum, epilogue) is round-0 verbatim.
// exp2f on Q pre-scaled by log2e (numerator and denominator use the same
// bf16-rounded value -> bounded error, same as round-0).
// s_setprio(1) wrapped around the PV MFMA cluster (T5, attn-positive regime).
// ---------------------------------------------------------------------------
#define ATTN_ITER(PS, KC0, KC1, KN0, KN1, SBN, SB, GUARD)                       \
  {                                                                             \
    short8 vva[4], vvb[4];                                                      \
    _Pragma("unroll")                                                           \
    for (int ks = 0; ks < 4; ++ks) {                                            \
      const int uu = 2 * ks + hh;                                               \
      vva[ks] = *(const short8*)&Vg[(size_t)c0 * 2048 + (SB) + uu * 8];         \
      vvb[ks] = *(const short8*)&Vg[(size_t)c1 * 2048 + (SB) + uu * 8];         \
    }                                                                           \
    if (GUARD) {                                                                \
      KN0 = *(const half8*)&Kt[((size_t)b * 2048 + (SBN) + 32 * u + m) * 32 + 8 * hh];      \
      KN1 = *(const half8*)&Kt[((size_t)b * 2048 + (SBN) + 32 * u + m) * 32 + 16 + 8 * hh]; \
    }                                                                           \
    {                                                                           \
      f32x16 qacc;                                                              \
      _Pragma("unroll")                                                         \
      for (int r = 0; r < 16; ++r) qacc[r] = 0.f;                               \
      qacc = __builtin_amdgcn_mfma_f32_32x32x16_f16(qf0, KC0, qacc, 0, 0, 0);   \
      qacc = __builtin_amdgcn_mfma_f32_32x32x16_f16(qf1, KC1, qacc, 0, 0, 0);   \
      _Pragma("unroll")                                                         \
      for (int r = 0; r < 16; ++r) {                                            \
        float e = exp2f(qacc[r]);                                               \
        unsigned short hb = f2bf(e);                                            \
        sacc[r] += bf2f(hb);                                                    \
        int qq = 32 * n + (r & 3) + 8 * (r >> 2) + 4 * hh;                      \
        PS[qq * 64 + (((scu + qq) & 7) << 3) + sco] = hb;                       \
      }                                                                         \
    }                                                                           \
    __syncthreads();                                                            \
    __builtin_amdgcn_s_setprio(1);                                              \
    _Pragma("unroll")                                                           \
    for (int ks = 0; ks < 4; ++ks) {                                            \
      const int uu = 2 * ks + hh;                                               \
      short8 pp0 = *(const short8*)&PS[m * 64 + (((uu + m) & 7) << 3)];         \
      short8 pp1 = *(const short8*)&PS[(32 + m) * 64 + (((uu + m) & 7) << 3)];  \
      pacc[0][0] = __builtin_amdgcn_mfma_f32_32x32x16_bf16(vva[ks], pp0, pacc[0][0], 0, 0, 0); \
      pacc[0][1] = __builtin_amdgcn_mfma_f32_32x32x16_bf16(vvb[ks], pp0, pacc[0][1], 0, 0, 0); \
      pacc[1][0] = __builtin_amdgcn_mfma_f32_32x32x16_bf16(vva[ks], pp1, pacc[1][0], 0, 0, 0); \
      pacc[1][1] = __builtin_amdgcn_mfma_f32_32x32x16_bf16(vvb[ks], pp1, pacc[1][1], 0, 0, 0); \
    }                                                                           \
    __builtin_amdgcn_s_setprio(0);                                              \
  }

__global__ __launch_bounds__(256, 2) void attn_kernel(
    const float* __restrict__ x, const char* __restrict__ ws,
    float* __restrict__ out) {
  __shared__ __align__(16) unsigned short PsA[64 * 64];    // 8 KB
  __shared__ __align__(16) unsigned short PsB[64 * 64];    // 8 KB  (total 16 KB)

  const unsigned short* Qt = (const unsigned short*)(ws + QTF_OFF);
  const unsigned short* Kt = (const unsigned short*)(ws + KTF_OFF);

  const int id = blockIdx.x;
  const int b  = ((id & 7) << 1) | ((id >> 3) & 1);   // 2 batches per XCD
  const int qt = id >> 4;
  const int t0 = qt * 64;
  const int tid  = threadIdx.x;
  const int w    = tid >> 6;
  const int lane = tid & 63;
  const int m    = lane & 31;
  const int hh   = lane >> 5;
  const int n    = w >> 1;       // q-tile for QK
  const int u    = w & 1;        // s-tile for QK
  const int c0   = 32 * w + m, c1 = 32 * (w + 4) + m;
  const int sc   = 32 * u + m, scu = sc >> 3, sco = sc & 7;

  const unsigned short* Vg =
      (const unsigned short*)(ws + VBF_OFF) + (size_t)b * 256 * 2048;

  // persistent Q frags; K frags tile 0 (register double-buffer)
  half8 qf0 = *(const half8*)&Qt[((size_t)b * 2048 + t0 + 32 * n + m) * 32 + 8 * hh];
  half8 qf1 = *(const half8*)&Qt[((size_t)b * 2048 + t0 + 32 * n + m) * 32 + 16 + 8 * hh];
  half8 ka0 = *(const half8*)&Kt[((size_t)b * 2048 + 32 * u + m) * 32 + 8 * hh];
  half8 ka1 = *(const half8*)&Kt[((size_t)b * 2048 + 32 * u + m) * 32 + 16 + 8 * hh];
  half8 kb0 = ka0, kb1 = ka1;

  f32x16 pacc[2][2];
  #pragma unroll
  for (int a = 0; a < 2; ++a)
    #pragma unroll
    for (int d = 0; d < 2; ++d)
      #pragma unroll
      for (int r = 0; r < 16; ++r) pacc[a][d][r] = 0.f;
  float sacc[16];
  #pragma unroll
  for (int r = 0; r < 16; ++r) sacc[r] = 0.f;

  for (int j = 0; j < 16; ++j) {
    const int sb0 = j * 128;
    const int sb1 = j * 128 + 64;
    ATTN_ITER(PsA, ka0, ka1, kb0, kb1, sb1, sb0, true)            // s-tile 2j
    ATTN_ITER(PsB, kb0, kb1, ka0, ka1, sb1 + 64, sb1, (j < 15))   // s-tile 2j+1
  }

  // ---- row sums (alias retired Ps buffers) ----
  float* sums = (float*)PsA;   // [64][2]
  float* invs = (float*)PsB;   // [64]
  #pragma unroll
  for (int r = 0; r < 16; ++r) {
    float v = sacc[r];
    #pragma unroll
    for (int off = 1; off < 32; off <<= 1) v += __shfl_xor(v, off, 64);
    if (m == 0) sums[(32 * n + (r & 3) + 8 * (r >> 2) + 4 * hh) * 2 + u] = v;
  }
  __syncthreads();
  if (tid < 64) invs[tid] = 1.0f / (sums[tid * 2] + sums[tid * 2 + 1]);
  __syncthreads();

  // ---- epilogue: out = pacc/sum + x, coalesced along t (col = q) ----
  const float inv0 = invs[m], inv1 = invs[32 + m];
  #pragma unroll
  for (int nn = 0; nn < 2; ++nn) {
    const float inv = nn ? inv1 : inv0;
    const int q = 32 * nn + m;
    #pragma unroll
    for (int mi = 0; mi < 2; ++mi) {
      const int cbase = 32 * (w + 4 * mi);
      #pragma unroll
      for (int r = 0; r < 16; ++r) {
        int c = cbase + (r & 3) + 8 * (r >> 2) + 4 * hh;
        size_t a = ((size_t)b * 256 + c) * 2048 + t0 + q;
        out[a] = pacc[nn][mi][r] * inv + x[a];
      }
    }
  }
}

// ---------------------------------------------------------------------------
extern "C" void kernel_launch(void* const* d_in, const int* in_sizes, int n_in,
                              void* d_out, int out_size, void* d_ws, size_t ws_size,
                              hipStream_t stream) {
  const float* x  = (const float*)d_in[0];
  const float* Wq = (const float*)d_in[1];
  const float* bq = (const float*)d_in[2];
  const float* Wk = (const float*)d_in[3];
  const float* bk = (const float*)d_in[4];
  const float* Wv = (const float*)d_in[5];
  const float* bv = (const float*)d_in[6];
  char* ws = (char*)d_ws;

  pack_kernel<<<320, 256, 0, stream>>>(Wq, bq, Wk, bk, Wv, bv, ws);
  proj_kernel<<<dim3(32, 16), 256, 0, stream>>>(x, ws);
  attn_kernel<<<512, 256, 0, stream>>>(x, ws, (float*)d_out);
}

// Round 4
// 178.896 us; speedup vs baseline: 1.1046x; 1.1046x over previous
//
#include <hip/hip_runtime.h>
#include <math.h>

typedef __attribute__((ext_vector_type(8)))  short          short8;
typedef __attribute__((ext_vector_type(8)))  unsigned short ushort8;
typedef __attribute__((ext_vector_type(8)))  _Float16       half8;
typedef __attribute__((ext_vector_type(16))) float          f32x16;

#define Bb 16
#define Cc 256
#define Tt 2048

#define LOG2E 1.4426950408889634f

// ---- workspace layout (bytes) ----
#define WH_OFF    0u                         // ushort [320][256] bf16-hi of W
#define WL_OFF    163840u                    // ushort [320][256] bf16-lo of W
#define BALL_OFF  327680u                    // fp32 [320]
#define QTF_OFF   328960u                    // ushort [16][2048][32] fp16 bits, [t][c]  (Q pre-scaled by log2e)
#define KTF_OFF   (QTF_OFF + 2097152u)
#define VBF_OFF   (KTF_OFF + 2097152u)       // ushort [16][256][2048] bf16 bits, [c][t]

__device__ __forceinline__ unsigned short f2bf(float f) {
  union { float f; unsigned u; } v; v.f = f;
  unsigned r = v.u + 0x7fffu + ((v.u >> 16) & 1u);   // RNE
  return (unsigned short)(r >> 16);
}
__device__ __forceinline__ float bf2f(unsigned short h) {
  union { unsigned u; float f; } v; v.u = ((unsigned)h) << 16;
  return v.f;
}
__device__ __forceinline__ unsigned short f2h(float f) {
  union { _Float16 h; unsigned short u; } v; v.h = (_Float16)f;
  return v.u;
}

// ---------------------------------------------------------------------------
// pack: W -> bf16 hi/lo planes [320][256] (+ bias fp32[320]).
// ---------------------------------------------------------------------------
__global__ __launch_bounds__(256) void pack_kernel(
    const float* __restrict__ Wq, const float* __restrict__ bq,
    const float* __restrict__ Wk, const float* __restrict__ bk,
    const float* __restrict__ Wv, const float* __restrict__ bv,
    char* ws) {
  unsigned short* WH = (unsigned short*)(ws + WH_OFF);
  unsigned short* WL = (unsigned short*)(ws + WL_OFF);
  float* ball = (float*)(ws + BALL_OFF);
  int o = blockIdx.x, c = threadIdx.x;
  float v;
  if (o < 32)      v = Wq[o * 256 + c];
  else if (o < 64) v = Wk[(o - 32) * 256 + c];
  else             v = Wv[(o - 64) * 256 + c];
  unsigned short hb = f2bf(v);
  WH[o * 256 + c] = hb;
  WL[o * 256 + c] = f2bf(v - bf2f(hb));
  if (c == 0) ball[o] = (o < 32) ? bq[o] : (o < 64 ? bk[o - 32] : bv[o - 64]);
}

// ---------------------------------------------------------------------------
// proj (MFMA): round-0 structure; Q epilogue pre-scales by log2e so attn
// can use native exp2 (v_exp_f32) without the per-element mul.
// ---------------------------------------------------------------------------
__global__ __launch_bounds__(256, 2) void proj_kernel(
    const float* __restrict__ x, char* ws) {
  __shared__ __align__(16) float xs[128 * 64];
  __shared__ __align__(16) unsigned short xth[64 * 136];
  __shared__ __align__(16) unsigned short xtl[64 * 136];

  const unsigned short* WH = (const unsigned short*)(ws + WH_OFF);
  const unsigned short* WL = (const unsigned short*)(ws + WL_OFF);
  const float* ball = (const float*)(ws + BALL_OFF);
  unsigned short* Qtf = (unsigned short*)(ws + QTF_OFF);
  unsigned short* Ktf = (unsigned short*)(ws + KTF_OFF);
  unsigned short* Vbf = (unsigned short*)(ws + VBF_OFF);

  const int b   = blockIdx.y;
  const int t0  = blockIdx.x * 64;
  const int tid = threadIdx.x;
  const int w    = tid >> 6;
  const int lane = tid & 63;
  const int m    = lane & 31;
  const int hh   = lane >> 5;

  const float* xb = x + ((size_t)b * 256) * 2048 + t0;

  f32x16 qkacc;
  f32x16 vacc[4];
  #pragma unroll
  for (int r = 0; r < 16; ++r) qkacc[r] = 0.f;
  #pragma unroll
  for (int j = 0; j < 4; ++j)
    #pragma unroll
    for (int r = 0; r < 16; ++r) vacc[j][r] = 0.f;

  #pragma unroll
  for (int r = 0; r < 8; ++r) {
    int idx = r * 256 + tid;
    int c = idx >> 4, f = idx & 15;
    *(float4*)&xs[c * 64 + 4 * f] = *(const float4*)&xb[(size_t)c * 2048 + 4 * f];
  }
  __syncthreads();

  const int tt = w & 1;
  const int qo = 32 * (w >> 1);

  #pragma unroll
  for (int half = 0; half < 2; ++half) {
    {
      const int t = lane;
      const int cq = w * 32;
      #pragma unroll
      for (int g = 0; g < 4; ++g) {
        ushort8 h8, l8;
        #pragma unroll
        for (int j = 0; j < 8; ++j) {
          float v = xs[(cq + g * 8 + j) * 64 + t];
          unsigned short hb = f2bf(v);
          h8[j] = hb;
          l8[j] = f2bf(v - bf2f(hb));
        }
        *(ushort8*)&xth[t * 136 + cq + g * 8] = h8;
        *(ushort8*)&xtl[t * 136 + cq + g * 8] = l8;
      }
    }
    __syncthreads();

    float4 pre[8];
    if (half == 0) {
      #pragma unroll
      for (int r = 0; r < 8; ++r) {
        int idx = r * 256 + tid;
        int c = idx >> 4, f = idx & 15;
        pre[r] = *(const float4*)&xb[(size_t)(128 + c) * 2048 + 4 * f];
      }
    }

    #pragma unroll
    for (int kk = 0; kk < 8; ++kk) {
      const int kl = kk * 16 + 8 * hh;
      const int kg = half * 128 + kl;
      short8 bh = *(const short8*)&xth[(32 * tt + m) * 136 + kl];
      short8 bl = *(const short8*)&xtl[(32 * tt + m) * 136 + kl];
      short8 ah = *(const short8*)&WH[(size_t)(qo + m) * 256 + kg];
      short8 al = *(const short8*)&WL[(size_t)(qo + m) * 256 + kg];
      qkacc = __builtin_amdgcn_mfma_f32_32x32x16_bf16(ah, bh, qkacc, 0, 0, 0);
      qkacc = __builtin_amdgcn_mfma_f32_32x32x16_bf16(ah, bl, qkacc, 0, 0, 0);
      qkacc = __builtin_amdgcn_mfma_f32_32x32x16_bf16(al, bh, qkacc, 0, 0, 0);
      #pragma unroll
      for (int j = 0; j < 4; ++j) {
        short8 av = *(const short8*)&WH[(size_t)(64 + 32 * (2 * j + (w >> 1)) + m) * 256 + kg];
        vacc[j] = __builtin_amdgcn_mfma_f32_32x32x16_bf16(av, bh, vacc[j], 0, 0, 0);
      }
    }

    if (half == 0) {
      #pragma unroll
      for (int r = 0; r < 8; ++r) {
        int idx = r * 256 + tid;
        int c = idx >> 4, f = idx & 15;
        *(float4*)&xs[c * 64 + 4 * f] = pre[r];
      }
      __syncthreads();
    }
  }

  // Q/K epilogue: single fp16 plane; Q pre-scaled by log2e
  {
    unsigned short* pt = (w < 2) ? Qtf : Ktf;
    const float qs = (w < 2) ? LOG2E : 1.0f;
    const int tcol = t0 + 32 * tt + m;
    #pragma unroll
    for (int r = 0; r < 16; ++r) {
      int orow = (r & 3) + 8 * (r >> 2) + 4 * hh;
      float v = (qkacc[r] + ball[qo + orow]) * qs;
      pt[((size_t)b * 2048 + tcol) * 32 + orow] = f2h(v);
    }
  }
  // V epilogue: bf16 [c][t]
  #pragma unroll
  for (int j = 0; j < 4; ++j) {
    const int vob = 64 + 32 * (2 * j + (w >> 1));
    #pragma unroll
    for (int r = 0; r < 16; ++r) {
      int orow = (r & 3) + 8 * (r >> 2) + 4 * hh;
      int o = vob + orow;
      float v = vacc[j][r] + ball[o];
      Vbf[((size_t)b * 256 + (o - 64)) * 2048 + t0 + 32 * tt + m] = f2bf(v);
    }
  }
}

// ---------------------------------------------------------------------------
// attn v7 = round-0 structure EXACTLY (V LDS staging restored: coalesced
// global->VGPR prefetch one iter ahead, swizzled land into Vs, PV gathers
// served from LDS). Round-3 taught us the direct-global V gather (64-line
// fan-out per instruction, consumed same-iter) is 18 us slower than the
// staged path. Only two validated tweaks on top of round 0:
//   - exp2f on log2e-prescaled Q (numerics proven identical in round 3)
//   - s_setprio(1) around the PV MFMA cluster (T5, attn-positive regime)
// ---------------------------------------------------------------------------
#define ATTN_ITER(VS, PS, KC0, KC1, KN0, KN1, SBN, GUARD)                       \
  {                                                                             \
    _Pragma("unroll")                                                           \
    for (int r = 0; r < 8; ++r) {                                               \
      int c = r * 32 + vc;                                                      \
      *(ushort8*)&VS[c * 64 + (((vk + c) & 7) << 3)] = vpre[r];                 \
    }                                                                           \
    if (GUARD) {                                                                \
      KN0 = *(const half8*)&Kt[((size_t)b * 2048 + (SBN) + 32 * u + m) * 32 + 8 * hh];      \
      KN1 = *(const half8*)&Kt[((size_t)b * 2048 + (SBN) + 32 * u + m) * 32 + 16 + 8 * hh]; \
      _Pragma("unroll")                                                         \
      for (int r = 0; r < 8; ++r) {                                             \
        int c = r * 32 + vc;                                                    \
        vpre[r] = *(const ushort8*)&Vg[(size_t)c * 2048 + (SBN) + vk * 8];      \
      }                                                                         \
    }                                                                           \
    {                                                                           \
      f32x16 qacc;                                                              \
      _Pragma("unroll")                                                         \
      for (int r = 0; r < 16; ++r) qacc[r] = 0.f;                               \
      qacc = __builtin_amdgcn_mfma_f32_32x32x16_f16(qf0, KC0, qacc, 0, 0, 0);   \
      qacc = __builtin_amdgcn_mfma_f32_32x32x16_f16(qf1, KC1, qacc, 0, 0, 0);   \
      _Pragma("unroll")                                                         \
      for (int r = 0; r < 16; ++r) {                                            \
        float e = exp2f(qacc[r]);                                               \
        unsigned short hb = f2bf(e);                                            \
        sacc[r] += bf2f(hb);                                                    \
        int qq = 32 * n + (r & 3) + 8 * (r >> 2) + 4 * hh;                      \
        PS[qq * 64 + (((scu + qq) & 7) << 3) + sco] = hb;                       \
      }                                                                         \
    }                                                                           \
    __syncthreads();                                                            \
    __builtin_amdgcn_s_setprio(1);                                              \
    _Pragma("unroll")                                                           \
    for (int ks = 0; ks < 4; ++ks) {                                            \
      const int uu = 2 * ks + hh;                                               \
      short8 pp0 = *(const short8*)&PS[m * 64 + (((uu + m) & 7) << 3)];         \
      short8 pp1 = *(const short8*)&PS[(32 + m) * 64 + (((uu + m) & 7) << 3)];  \
      short8 vv0 = *(const short8*)&VS[c0 * 64 + (((uu + c0) & 7) << 3)];       \
      short8 vv1 = *(const short8*)&VS[c1 * 64 + (((uu + c1) & 7) << 3)];       \
      pacc[0][0] = __builtin_amdgcn_mfma_f32_32x32x16_bf16(vv0, pp0, pacc[0][0], 0, 0, 0); \
      pacc[0][1] = __builtin_amdgcn_mfma_f32_32x32x16_bf16(vv1, pp0, pacc[0][1], 0, 0, 0); \
      pacc[1][0] = __builtin_amdgcn_mfma_f32_32x32x16_bf16(vv0, pp1, pacc[1][0], 0, 0, 0); \
      pacc[1][1] = __builtin_amdgcn_mfma_f32_32x32x16_bf16(vv1, pp1, pacc[1][1], 0, 0, 0); \
    }                                                                           \
    __builtin_amdgcn_s_setprio(0);                                              \
  }

__global__ __launch_bounds__(256, 2) void attn_kernel(
    const float* __restrict__ x, const char* __restrict__ ws,
    float* __restrict__ out) {
  __shared__ __align__(16) unsigned short VsA[256 * 64];   // 32 KB
  __shared__ __align__(16) unsigned short VsB[256 * 64];   // 32 KB
  __shared__ __align__(16) unsigned short PsA[64 * 64];    // 8 KB
  __shared__ __align__(16) unsigned short PsB[64 * 64];    // 8 KB  (total 80 KB)

  const unsigned short* Qt = (const unsigned short*)(ws + QTF_OFF);
  const unsigned short* Kt = (const unsigned short*)(ws + KTF_OFF);

  const int id = blockIdx.x;
  const int b  = ((id & 7) << 1) | ((id >> 3) & 1);   // 2 batches per XCD
  const int qt = id >> 4;
  const int t0 = qt * 64;
  const int tid  = threadIdx.x;
  const int w    = tid >> 6;
  const int lane = tid & 63;
  const int m    = lane & 31;
  const int hh   = lane >> 5;
  const int n    = w >> 1;       // q-tile for QK
  const int u    = w & 1;        // s-tile for QK
  const int vk   = tid & 7, vc = tid >> 3;
  const int c0   = 32 * w + m, c1 = 32 * (w + 4) + m;
  const int sc   = 32 * u + m, scu = sc >> 3, sco = sc & 7;

  const unsigned short* Vg =
      (const unsigned short*)(ws + VBF_OFF) + (size_t)b * 256 * 2048;

  // persistent Q frags; K frags tile 0; V tile 0 into vpre
  half8 qf0 = *(const half8*)&Qt[((size_t)b * 2048 + t0 + 32 * n + m) * 32 + 8 * hh];
  half8 qf1 = *(const half8*)&Qt[((size_t)b * 2048 + t0 + 32 * n + m) * 32 + 16 + 8 * hh];
  half8 ka0 = *(const half8*)&Kt[((size_t)b * 2048 + 32 * u + m) * 32 + 8 * hh];
  half8 ka1 = *(const half8*)&Kt[((size_t)b * 2048 + 32 * u + m) * 32 + 16 + 8 * hh];
  half8 kb0 = ka0, kb1 = ka1;
  ushort8 vpre[8];
  #pragma unroll
  for (int r = 0; r < 8; ++r) {
    int c = r * 32 + vc;
    vpre[r] = *(const ushort8*)&Vg[(size_t)c * 2048 + vk * 8];
  }

  f32x16 pacc[2][2];
  #pragma unroll
  for (int a = 0; a < 2; ++a)
    #pragma unroll
    for (int d = 0; d < 2; ++d)
      #pragma unroll
      for (int r = 0; r < 16; ++r) pacc[a][d][r] = 0.f;
  float sacc[16];
  #pragma unroll
  for (int r = 0; r < 16; ++r) sacc[r] = 0.f;

  for (int j = 0; j < 16; ++j) {
    const int sb1 = j * 128 + 64;
    const int sb2 = j * 128 + 128;
    ATTN_ITER(VsA, PsA, ka0, ka1, kb0, kb1, sb1, true)        // s-tile 2j
    ATTN_ITER(VsB, PsB, kb0, kb1, ka0, ka1, sb2, (j < 15))    // s-tile 2j+1
  }

  // ---- row sums (alias retired Ps buffers) ----
  float* sums = (float*)PsA;   // [64][2]
  float* invs = (float*)PsB;   // [64]
  #pragma unroll
  for (int r = 0; r < 16; ++r) {
    float v = sacc[r];
    #pragma unroll
    for (int off = 1; off < 32; off <<= 1) v += __shfl_xor(v, off, 64);
    if (m == 0) sums[(32 * n + (r & 3) + 8 * (r >> 2) + 4 * hh) * 2 + u] = v;
  }
  __syncthreads();
  if (tid < 64) invs[tid] = 1.0f / (sums[tid * 2] + sums[tid * 2 + 1]);
  __syncthreads();

  // ---- epilogue: out = pacc/sum + x, coalesced along t (col = q) ----
  const float inv0 = invs[m], inv1 = invs[32 + m];
  #pragma unroll
  for (int nn = 0; nn < 2; ++nn) {
    const float inv = nn ? inv1 : inv0;
    const int q = 32 * nn + m;
    #pragma unroll
    for (int mi = 0; mi < 2; ++mi) {
      const int cbase = 32 * (w + 4 * mi);
      #pragma unroll
      for (int r = 0; r < 16; ++r) {
        int c = cbase + (r & 3) + 8 * (r >> 2) + 4 * hh;
        size_t a = ((size_t)b * 256 + c) * 2048 + t0 + q;
        out[a] = pacc[nn][mi][r] * inv + x[a];
      }
    }
  }
}

// ---------------------------------------------------------------------------
extern "C" void kernel_launch(void* const* d_in, const int* in_sizes, int n_in,
                              void* d_out, int out_size, void* d_ws, size_t ws_size,
                              hipStream_t stream) {
  const float* x  = (const float*)d_in[0];
  const float* Wq = (const float*)d_in[1];
  const float* bq = (const float*)d_in[2];
  const float* Wk = (const float*)d_in[3];
  const float* bk = (const float*)d_in[4];
  const float* Wv = (const float*)d_in[5];
  const float* bv = (const float*)d_in[6];
  char* ws = (char*)d_ws;

  pack_kernel<<<320, 256, 0, stream>>>(Wq, bq, Wk, bk, Wv, bv, ws);
  proj_kernel<<<dim3(32, 16), 256, 0, stream>>>(x, ws);
  attn_kernel<<<512, 256, 0, stream>>>(x, ws, (float*)d_out);
}